// Round 9
// baseline (60.249 us; speedup 1.0000x reference)
//
#include <hip/hip_runtime.h>
#include <math.h>

// Fused: out[b,oc,y,x] = max_{dy,dx} min(xmax[b,y+dy-2,x+dx-2], k[oc,dy,dx])
// xmax = channel-max over C=32; OOB = -inf.
// x (16,32,256,256) f32, k (32,5,5) f32, out (16,32,256,256) f32.
//
// One block = 32x8 output tile, all 32 oc. 4096 blocks (~16/CU grid vs ~8
// resident) -> >=2 staggered generations so phase1 reads of gen-k overlap
// phase2 compute/writes of gen-(k-1) (round-8 lockstep fix).
// Phase 1: channel-max of 12x40 halo tile (origin x0-4,y0-2) -> LDS, -inf OOB.
// Phase 2: wave = 8 oc (taps s_load, wave-uniform); lane = 4px x 1row;
//          window 5x8 floats (40 VGPR) via ds_read_b64, reused across 8 oc.
// Output via nontemporal stores (keeps input LLC-resident).

#define BATCH 16
#define CH    32
#define OCH   32
#define HH    256
#define WW    256
#define HWSZ  (HH * WW)
#define TW    32
#define TH    8
#define LH    12              // TH + 4
#define LW    42              // stride: 40 data cols + 2 pad; rows 8B-aligned
#define NWG   (BATCH * (HH / TH) * (WW / TW))   // 4096

typedef float floatx4 __attribute__((ext_vector_type(4)));

__device__ __forceinline__ float vmax3(float a, float b, float c) {
    float d;
    asm("v_max3_f32 %0, %1, %2, %3" : "=v"(d) : "v"(a), "v"(b), "v"(c));
    return d;
}

__global__ __launch_bounds__(256, 2) void fused_maxmin_kernel(const float* __restrict__ x,
                                                              const float* __restrict__ kk,
                                                              float* __restrict__ out) {
    __shared__ float xmt[LH][LW];
    int tid = threadIdx.x;
    int bid = blockIdx.x;
    int swz = (bid & 7) * (NWG >> 3) + (bid >> 3);   // XCD-chunked, bijective (4096%8==0)
    int b   = swz >> 8;                              // 256 tiles/batch
    int t2  = swz & 255;
    int ty  = t2 >> 3;                               // 0..31
    int tx  = t2 & 7;                                // 0..7

    const float NI = -INFINITY;

    // ---- Phase 1: channel max of 12 rows x 10 float4 granules ----
    if (tid < 120) {
        int pr = tid / 10;                           // LDS row 0..11
        int pc = tid % 10;                           // granule 0..9
        int c4 = tx * 8 - 1 + pc;                    // global float4 col
        int rw = ty * TH - 2 + pr;                   // global row
        bool valid = (c4 >= 0) && (c4 < WW / 4) && (rw >= 0) && (rw < HH);
        int c4c = c4 < 0 ? 0 : (c4 > WW / 4 - 1 ? WW / 4 - 1 : c4);
        int rwc = rw < 0 ? 0 : (rw > HH - 1 ? HH - 1 : rw);
        const float4* src = (const float4*)x + (size_t)b * CH * (HWSZ / 4)
                          + (size_t)rwc * (WW / 4) + c4c;
        float4 m = src[0];
#pragma unroll
        for (int c = 1; c < CH; ++c) {
            float4 v = src[(size_t)c * (HWSZ / 4)];
            m.x = fmaxf(m.x, v.x);
            m.y = fmaxf(m.y, v.y);
            m.z = fmaxf(m.z, v.z);
            m.w = fmaxf(m.w, v.w);
        }
        if (!valid) { m.x = NI; m.y = NI; m.z = NI; m.w = NI; }
        *(float2*)&xmt[pr][4 * pc]     = make_float2(m.x, m.y);   // stride 42 -> 8B align
        *(float2*)&xmt[pr][4 * pc + 2] = make_float2(m.z, m.w);
    }
    __syncthreads();

    // ---- Phase 2 ----
    int xg = tid & 7;                                // 8 groups x 4 px
    int rw = (tid >> 3) & 7;                         // 8 rows
    int wv = __builtin_amdgcn_readfirstlane(tid >> 6);   // wave -> oc 8*wv..8*wv+7

    // Window: LDS rows rw..rw+4, cols 4xg+2..4xg+9 (8B-aligned float2 reads).
    float w[5][8];
#pragma unroll
    for (int r = 0; r < 5; ++r) {
        const float* rp = &xmt[rw + r][4 * xg + 2];
#pragma unroll
        for (int s = 0; s < 4; ++s)
            *(float2*)&w[r][2 * s] = *(const float2*)(rp + 2 * s);
    }

    size_t obase = (size_t)(b * OCH + wv * 8) * HWSZ
                 + (size_t)(ty * TH + rw) * WW + tx * TW + 4 * xg;

    for (int o = 0; o < 8; ++o) {
        const float* kw = kk + (wv * 8 + o) * 25;    // wave-uniform -> s_load
        float kr[25];
#pragma unroll
        for (int i = 0; i < 25; ++i) kr[i] = kw[i];

        float a[4];
#pragma unroll
        for (int j = 0; j < 4; ++j) {
            float m[25];
#pragma unroll
            for (int dy = 0; dy < 5; ++dy)
#pragma unroll
                for (int dx = 0; dx < 5; ++dx)
                    m[dy * 5 + dx] = fminf(w[dy][j + dx], kr[dy * 5 + dx]);
            float t0 = vmax3(m[0],  m[1],  m[2]);
            float t1 = vmax3(m[3],  m[4],  m[5]);
            float t2 = vmax3(m[6],  m[7],  m[8]);
            float t3 = vmax3(m[9],  m[10], m[11]);
            float t4 = vmax3(m[12], m[13], m[14]);
            float t5 = vmax3(m[15], m[16], m[17]);
            float t6 = vmax3(m[18], m[19], m[20]);
            float t7 = vmax3(m[21], m[22], m[23]);
            float u0 = vmax3(t0, t1, t2);
            float u1 = vmax3(t3, t4, t5);
            float u2 = vmax3(t6, t7, m[24]);
            a[j] = vmax3(u0, u1, u2);
        }
        floatx4 ov = { a[0], a[1], a[2], a[3] };
        __builtin_nontemporal_store(ov, (floatx4*)(out + obase + (size_t)o * HWSZ));
    }
}

extern "C" void kernel_launch(void* const* d_in, const int* in_sizes, int n_in,
                              void* d_out, int out_size, void* d_ws, size_t ws_size,
                              hipStream_t stream) {
    const float* x  = (const float*)d_in[0];
    const float* kk = (const float*)d_in[1];
    float* out      = (float*)d_out;
    fused_maxmin_kernel<<<NWG, 256, 0, stream>>>(x, kk, out);
}

// Round 10
// 58.435 us; speedup vs baseline: 1.0310x; 1.0310x over previous
//
#include <hip/hip_runtime.h>
#include <math.h>

// Fused: out[b,oc,y,x] = max_{dy,dx} min(xmax[b,y+dy-2,x+dx-2], k[oc,dy,dx])
// xmax = channel-max over C=32; OOB = -inf.
// x (16,32,256,256) f32, k (32,5,5) f32, out (16,32,256,256) f32.
//
// Block = TWO vertically-stacked 32x16 tiles (T0,T1), 1024 blocks.
// Pipeline: phase1(T0) | barrier | {T1 chanmax loads interleaved with T0
// conv, 4 channels per oc-chunk} | barrier | conv(T1).
// The T1 global loads are independent of T0's conv (separate LDS buffer),
// so ~150 VALU ops sit between load issue and consume -> latency hidden.

#define BATCH 16
#define CH    32
#define OCH   32
#define HH    256
#define WW    256
#define HWSZ  (HH * WW)
#define TW    32
#define TH    16
#define LH    20              // TH + 4 halo rows
#define LW    42              // 40 data cols + 2 pad (8B-aligned rows)
#define NWG   (BATCH * (HH / (2 * TH)) * (WW / TW))   // 1024

typedef float floatx4 __attribute__((ext_vector_type(4)));

__device__ __forceinline__ float vmax3(float a, float b, float c) {
    float d;
    asm("v_max3_f32 %0, %1, %2, %3" : "=v"(d) : "v"(a), "v"(b), "v"(c));
    return d;
}

// conv for one oc: 2 rows x 4 px from the 6x8 register window.
__device__ __forceinline__ void conv_oc(const float (&w)[6][8], const float* __restrict__ kk,
                                        int oc, float* __restrict__ out, size_t obq) {
    const float* kw = kk + oc * 25;       // wave-uniform -> s_load
    float kr[25];
#pragma unroll
    for (int i = 0; i < 25; ++i) kr[i] = kw[i];
#pragma unroll
    for (int r = 0; r < 2; ++r) {
        float a[4];
#pragma unroll
        for (int j = 0; j < 4; ++j) {
            float mm[25];
#pragma unroll
            for (int dy = 0; dy < 5; ++dy)
#pragma unroll
                for (int dx = 0; dx < 5; ++dx)
                    mm[dy * 5 + dx] = fminf(w[r + dy][j + dx], kr[dy * 5 + dx]);
            float t0 = vmax3(mm[0],  mm[1],  mm[2]);
            float t1 = vmax3(mm[3],  mm[4],  mm[5]);
            float t2 = vmax3(mm[6],  mm[7],  mm[8]);
            float t3 = vmax3(mm[9],  mm[10], mm[11]);
            float t4 = vmax3(mm[12], mm[13], mm[14]);
            float t5 = vmax3(mm[15], mm[16], mm[17]);
            float t6 = vmax3(mm[18], mm[19], mm[20]);
            float t7 = vmax3(mm[21], mm[22], mm[23]);
            a[j] = vmax3(vmax3(t0, t1, t2), vmax3(t3, t4, t5), vmax3(t6, t7, mm[24]));
        }
        floatx4 ov = { a[0], a[1], a[2], a[3] };
        __builtin_nontemporal_store(ov, (floatx4*)(out + obq + (size_t)r * WW));
    }
}

__global__ __launch_bounds__(256, 2) void fused_maxmin_kernel(const float* __restrict__ x,
                                                              const float* __restrict__ kk,
                                                              float* __restrict__ out) {
    __shared__ float xmt[2][LH][LW];
    int tid = threadIdx.x;
    int bid = blockIdx.x;
    int swz = (bid & 7) * (NWG >> 3) + (bid >> 3);   // XCD-chunked, bijective (1024%8==0)
    int b   = swz >> 6;                              // 64 block-regions per batch
    int t2  = swz & 63;
    int ty2 = t2 >> 3;                               // 0..7: rows ty2*32 .. +31
    int tx  = t2 & 7;

    const float NI = -INFINITY;

    // phase1 granule coords (tid < 200): 20 rows x 10 float4 granules
    int pr = tid / 10, pc = tid % 10;
    int c4 = tx * 8 - 1 + pc;
    bool cvalid = (c4 >= 0) && (c4 < WW / 4);
    int c4c = c4 < 0 ? 0 : (c4 > WW / 4 - 1 ? WW / 4 - 1 : c4);
    const float4* xb4 = (const float4*)x + (size_t)b * CH * (HWSZ / 4);

    // ---- phase1(T0): rows ty2*32-2 .. +17 ----
    if (tid < 200) {
        int rw = ty2 * 32 - 2 + pr;
        bool valid = cvalid && (rw >= 0) && (rw < HH);
        int rwc = rw < 0 ? 0 : (rw > HH - 1 ? HH - 1 : rw);
        const float4* src = xb4 + (size_t)rwc * (WW / 4) + c4c;
        float4 m = src[0];
#pragma unroll
        for (int c = 1; c < CH; ++c) {
            float4 v = src[(size_t)c * (HWSZ / 4)];
            m.x = fmaxf(m.x, v.x); m.y = fmaxf(m.y, v.y);
            m.z = fmaxf(m.z, v.z); m.w = fmaxf(m.w, v.w);
        }
        if (!valid) { m.x = NI; m.y = NI; m.z = NI; m.w = NI; }
        *(float2*)&xmt[0][pr][4 * pc]     = make_float2(m.x, m.y);
        *(float2*)&xmt[0][pr][4 * pc + 2] = make_float2(m.z, m.w);
    }
    __syncthreads();

    // phase2 thread mapping: 4 px x 2 rows x 8 oc
    int xg = tid & 7;
    int rg = (tid >> 3) & 7;
    int wv = __builtin_amdgcn_readfirstlane(tid >> 6);

    // T1 phase1 source (rows ty2*32+14 .. +33; >=14 so no low clamp)
    int rw1 = ty2 * 32 + 14 + pr;
    bool valid1 = cvalid && (rw1 < HH);
    int rwc1 = rw1 > HH - 1 ? HH - 1 : rw1;
    const float4* src1 = xb4 + (size_t)rwc1 * (WW / 4) + c4c;

    // T0 window: LDS rows 2rg..2rg+5, cols 4xg+2..4xg+9
    float w[6][8];
#pragma unroll
    for (int r = 0; r < 6; ++r) {
        const float* rp = &xmt[0][2 * rg + r][4 * xg + 2];
#pragma unroll
        for (int s = 0; s < 4; ++s)
            *(float2*)&w[r][2 * s] = *(const float2*)(rp + 2 * s);
    }

    size_t ob0 = (size_t)(b * OCH + wv * 8) * HWSZ
               + (size_t)(ty2 * 32 + 2 * rg) * WW + tx * TW + 4 * xg;

    // ---- interleaved: T1 chanmax (4 ch/chunk) + T0 conv (1 oc/chunk) ----
    float4 macc = make_float4(NI, NI, NI, NI);
    bool act = tid < 200;
#pragma unroll
    for (int o = 0; o < 8; ++o) {
        float4 v0, v1, v2, v3;
        if (act) {
            v0 = src1[(size_t)(4 * o + 0) * (HWSZ / 4)];
            v1 = src1[(size_t)(4 * o + 1) * (HWSZ / 4)];
            v2 = src1[(size_t)(4 * o + 2) * (HWSZ / 4)];
            v3 = src1[(size_t)(4 * o + 3) * (HWSZ / 4)];
        }
        conv_oc(w, kk, wv * 8 + o, out, ob0 + (size_t)o * HWSZ);
        if (act) {
            macc.x = fmaxf(macc.x, fmaxf(fmaxf(v0.x, v1.x), fmaxf(v2.x, v3.x)));
            macc.y = fmaxf(macc.y, fmaxf(fmaxf(v0.y, v1.y), fmaxf(v2.y, v3.y)));
            macc.z = fmaxf(macc.z, fmaxf(fmaxf(v0.z, v1.z), fmaxf(v2.z, v3.z)));
            macc.w = fmaxf(macc.w, fmaxf(fmaxf(v0.w, v1.w), fmaxf(v2.w, v3.w)));
        }
    }
    if (act) {
        if (!valid1) { macc.x = NI; macc.y = NI; macc.z = NI; macc.w = NI; }
        *(float2*)&xmt[1][pr][4 * pc]     = make_float2(macc.x, macc.y);
        *(float2*)&xmt[1][pr][4 * pc + 2] = make_float2(macc.z, macc.w);
    }
    __syncthreads();

    // ---- phase2(T1) ----
#pragma unroll
    for (int r = 0; r < 6; ++r) {
        const float* rp = &xmt[1][2 * rg + r][4 * xg + 2];
#pragma unroll
        for (int s = 0; s < 4; ++s)
            *(float2*)&w[r][2 * s] = *(const float2*)(rp + 2 * s);
    }
    size_t ob1 = ob0 + (size_t)16 * WW;
#pragma unroll
    for (int o = 0; o < 8; ++o)
        conv_oc(w, kk, wv * 8 + o, out, ob1 + (size_t)o * HWSZ);
}

extern "C" void kernel_launch(void* const* d_in, const int* in_sizes, int n_in,
                              void* d_out, int out_size, void* d_ws, size_t ws_size,
                              hipStream_t stream) {
    const float* x  = (const float*)d_in[0];
    const float* kk = (const float*)d_in[1];
    float* out      = (float*)d_out;
    fused_maxmin_kernel<<<NWG, 256, 0, stream>>>(x, kk, out);
}